// Round 3
// baseline (876.051 us; speedup 1.0000x reference)
//
#include <hip/hip_runtime.h>
#include <hip/hip_bf16.h>

#define D_MODEL 1024
#define N_HEADS 16
#define HEAD_DIM 64
#define NUM_RULES 64
#define RANK 8
#define SHARED_RANK 32
#define NUM_BLOCKS_ 16
#define BB 4
#define SS 1024
#define NTOK (BB*SS)

__device__ __forceinline__ float bf2f(unsigned short u) {
  unsigned int i = ((unsigned int)u) << 16;
  float f;
  __builtin_memcpy(&f, &i, 4);
  return f;
}
__device__ __forceinline__ unsigned short f2bf(float f) {
  __hip_bfloat16 h = __float2bfloat16(f);
  unsigned short u;
  __builtin_memcpy(&u, &h, 2);
  return u;
}
template<bool BF>
__device__ __forceinline__ float ldw(const void* p, size_t i) {
  if (BF) return bf2f(((const unsigned short*)p)[i]);
  else    return ((const float*)p)[i];
}

// ---------------------------------------------------------------------------
// Dtype detection (unchanged from passing R2 version)
// ---------------------------------------------------------------------------
__global__ void detect_kernel(const unsigned short* __restrict__ x, int* __restrict__ flag) {
  const int lane = threadIdx.x;  // 64
  int good = 0;
  for (int i = 0; i < 4; i++) {
    unsigned short u = x[lane*4 + i];
    int e = (u >> 7) & 0xFF;
    good += (e == 0 || (e >= 100 && e <= 145)) ? 1 : 0;
  }
  for (int off = 32; off; off >>= 1) good += __shfl_xor(good, off);
  if (lane == 0) flag[0] = (good >= 224) ? 1 : 0;
}

// ---------------------------------------------------------------------------
// Precompute: M[64][64] and sel[4][64][16] (unchanged)
// ---------------------------------------------------------------------------
template<bool BF>
__device__ __forceinline__ void precompute_body(
    const void* rq, const void* rk,
    const void* qlg, const void* klg, const void* vlg, const void* olg,
    float* __restrict__ M, float* __restrict__ sel)
{
  __shared__ float rqn[64][8], rkn[64][8];
  const int tid = threadIdx.x;  // 256
  if (tid < 64) {
    float v[8]; float s = 0.f;
    for (int i = 0; i < 8; i++) { v[i] = ldw<BF>(rq, tid*8+i); s += v[i]*v[i]; }
    float inv = 1.0f / fmaxf(sqrtf(s), 1e-12f);
    for (int i = 0; i < 8; i++) rqn[tid][i] = v[i]*inv;
  } else if (tid < 128) {
    int r = tid - 64;
    float v[8]; float s = 0.f;
    for (int i = 0; i < 8; i++) { v[i] = ldw<BF>(rk, r*8+i); s += v[i]*v[i]; }
    float inv = 1.0f / fmaxf(sqrtf(s), 1e-12f);
    for (int i = 0; i < 8; i++) rkn[r][i] = v[i]*inv;
  }
  __syncthreads();
  const float LN8 = 2.0794415416798357f;  // 1/tau = ln(8)
  for (int idx = tid; idx < 64*64; idx += 256) {
    int i = idx >> 6, j = idx & 63;
    float d = 0.f;
    for (int t = 0; t < 8; t++) d += rqn[i][t]*rkn[j][t];
    M[idx] = d * LN8;
  }
  const void* lgs[4] = {qlg, klg, vlg, olg};
  {
    int p = tid >> 6, r = tid & 63; (void)p;
    const void* lg = lgs[tid >> 6];
    float e[NUM_BLOCKS_]; float mx = -1e30f;
    for (int b = 0; b < NUM_BLOCKS_; b++) {
      e[b] = ldw<BF>(lg, r*NUM_BLOCKS_ + b) * 4.0f;
      mx = fmaxf(mx, e[b]);
    }
    float s = 0.f;
    for (int b = 0; b < NUM_BLOCKS_; b++) { e[b] = expf(e[b]-mx); s += e[b]; }
    float inv = 1.0f/s;
    for (int b = 0; b < NUM_BLOCKS_; b++) sel[tid*NUM_BLOCKS_+b] = e[b]*inv;
  }
}

__global__ void precompute_kernel(
    const void* rq, const void* rk,
    const void* qlg, const void* klg, const void* vlg, const void* olg,
    float* M, float* sel, const int* __restrict__ flag)
{
  if (*flag) precompute_body<true >(rq, rk, qlg, klg, vlg, olg, M, sel);
  else       precompute_body<false>(rq, rk, qlg, klg, vlg, olg, M, sel);
}

// ---------------------------------------------------------------------------
// Rule-aware projection, 8 tokens per block (grid NTOK/8, 256 threads).
// Weight loads amortized over 8 tokens; pair epilogue with fused RoPE and
// direct global stores (float2 / ushort2).
// ---------------------------------------------------------------------------
template<bool IN_BF, bool W_BF, bool OUT_BF>
__device__ __forceinline__ void proj_body(
    const void* __restrict__ xin_, const int* __restrict__ rules,
    const void* __restrict__ si, const void* __restrict__ so,
    const void* __restrict__ ri, const void* __restrict__ ro,
    const float* __restrict__ sel, void* __restrict__ out_, int do_rope)
{
  const int n0 = blockIdx.x * 8;
  const int tid = threadIdx.x;
  __shared__ float xs[8][D_MODEL + 4];   // +4 pad: spread h-stage banks
  __shared__ float tpart[8][32][8];      // [c][j][t]
  __shared__ float tt[32][8];            // [j][t]  (transposed for b128 reads)
  __shared__ float hh[8][16][8];         // [t][blk][r]
  __shared__ float selb[8][16];
  __shared__ int rl[8];

  // ---- load x rows (8 x 1024) ----
  #pragma unroll
  for (int t = 0; t < 8; t++) {
    float4 f;
    if (IN_BF) {
      ushort4 u = ((const ushort4*)((const unsigned short*)xin_ + (size_t)(n0 + t)*D_MODEL))[tid];
      f.x = bf2f(u.x); f.y = bf2f(u.y); f.z = bf2f(u.z); f.w = bf2f(u.w);
    } else {
      f = ((const float4*)xin_)[(size_t)(n0 + t)*(D_MODEL/4) + tid];
    }
    *(float4*)&xs[t][tid*4] = f;
  }
  if (tid < 8) rl[tid] = rules[n0 + tid];
  __syncthreads();
  if (tid < 128) { int t = tid >> 4, blk = tid & 15; selb[t][blk] = sel[rl[t]*NUM_BLOCKS_ + blk]; }

  // ---- stage t: t[tok][j] = sum_d x[tok][d]*si[d][j]; thread (c=tid>>5, j=tid&31) ----
  {
    const int c = tid >> 5, j = tid & 31;
    float p[8];
    #pragma unroll
    for (int t = 0; t < 8; t++) p[t] = 0.f;
    for (int d4 = 0; d4 < 32; d4++) {
      const int d = c*128 + d4*4;
      float w0 = ldw<W_BF>(si, (size_t)(d + 0)*SHARED_RANK + j);
      float w1 = ldw<W_BF>(si, (size_t)(d + 1)*SHARED_RANK + j);
      float w2 = ldw<W_BF>(si, (size_t)(d + 2)*SHARED_RANK + j);
      float w3 = ldw<W_BF>(si, (size_t)(d + 3)*SHARED_RANK + j);
      #pragma unroll
      for (int t = 0; t < 8; t++) {
        float4 xv = *(const float4*)&xs[t][d];
        p[t] += xv.x*w0 + xv.y*w1 + xv.z*w2 + xv.w*w3;
      }
    }
    #pragma unroll
    for (int t = 0; t < 8; t++) tpart[c][j][t] = p[t];
  }
  __syncthreads();

  // ---- reduce tt (transposed) ----
  {
    const int t = tid >> 5, j = tid & 31;
    float s = 0.f;
    #pragma unroll
    for (int c = 0; c < 8; c++) s += tpart[c][j][t];
    tt[j][t] = s;
  }
  // ---- hh[t][blk][r] = sum_k x[t][blk*64+k]*ri[rule][k][r]; thread (t,blk,r0) ----
  {
    const int t = tid >> 5, blk = (tid >> 1) & 15, r0 = (tid & 1)*4;
    const int rule = rl[t];
    float a0=0.f, a1=0.f, a2=0.f, a3=0.f;
    for (int k4 = 0; k4 < 16; k4++) {
      const int kk = ((k4 + blk) & 15) * 4;   // rotate to spread LDS banks
      float4 xv = *(const float4*)&xs[t][blk*64 + kk];
      #pragma unroll
      for (int q = 0; q < 4; q++) {
        const int k = kk + q;
        float w0,w1,w2,w3;
        if (W_BF) {
          ushort4 u = *(const ushort4*)((const unsigned short*)ri + (size_t)rule*512 + (size_t)k*8 + r0);
          w0=bf2f(u.x); w1=bf2f(u.y); w2=bf2f(u.z); w3=bf2f(u.w);
        } else {
          float4 u = *(const float4*)((const float*)ri + (size_t)rule*512 + (size_t)k*8 + r0);
          w0=u.x; w1=u.y; w2=u.z; w3=u.w;
        }
        float xq = (q==0)?xv.x:((q==1)?xv.y:((q==2)?xv.z:xv.w));
        a0 += xq*w0; a1 += xq*w1; a2 += xq*w2; a3 += xq*w3;
      }
    }
    hh[t][blk][r0+0]=a0; hh[t][blk][r0+1]=a1; hh[t][blk][r0+2]=a2; hh[t][blk][r0+3]=a3;
  }
  __syncthreads();

  // ---- base + lowrank + RoPE + store; pair p -> channels (2p, 2p+1) ----
  for (int u = 0; u < 2; u++) {
    const int p = tid + u*256;
    const int ch0 = 2*p;
    const int blk = p >> 5;
    const int ii = p & 31;       // rope pair index within head
    float s0[8], s1[8];
    #pragma unroll
    for (int t = 0; t < 8; t++) { s0[t]=0.f; s1[t]=0.f; }
    for (int j = 0; j < 32; j++) {
      float w0, w1;
      if (W_BF) {
        ushort2 w = *(const ushort2*)((const unsigned short*)so + (size_t)j*D_MODEL + ch0);
        w0 = bf2f(w.x); w1 = bf2f(w.y);
      } else {
        float2 w = *(const float2*)((const float*)so + (size_t)j*D_MODEL + ch0);
        w0 = w.x; w1 = w.y;
      }
      float tv[8];
      *(float4*)&tv[0] = *(const float4*)&tt[j][0];
      *(float4*)&tv[4] = *(const float4*)&tt[j][4];
      #pragma unroll
      for (int t = 0; t < 8; t++) { s0[t] += tv[t]*w0; s1[t] += tv[t]*w1; }
    }
    float invf = 0.f;
    if (do_rope) invf = expf(-(float)(2*ii) * (9.210340371976184f/64.0f));
    const int tc = ch0 & 63;
    #pragma unroll
    for (int t = 0; t < 8; t++) {
      const int rule = rl[t];
      float hv[8];
      *(float4*)&hv[0] = *(const float4*)&hh[t][blk][0];
      *(float4*)&hv[4] = *(const float4*)&hh[t][blk][4];
      float a0=0.f, a1=0.f;
      #pragma unroll
      for (int r = 0; r < 8; r++) {
        float w0,w1;
        if (W_BF) {
          ushort2 w = *(const ushort2*)((const unsigned short*)ro + (size_t)rule*512 + (size_t)r*64 + tc);
          w0=bf2f(w.x); w1=bf2f(w.y);
        } else {
          float2 w = *(const float2*)((const float*)ro + (size_t)rule*512 + (size_t)r*64 + tc);
          w0=w.x; w1=w.y;
        }
        a0 += hv[r]*w0; a1 += hv[r]*w1;
      }
      float sb = selb[t][blk];
      float e = s0[t] + a0*sb;
      float o = s1[t] + a1*sb;
      if (do_rope) {
        float f = (float)((n0 + t) & (SS-1)) * invf;
        float sn, cs;
        sincosf(f, &sn, &cs);
        float e2 = e*cs - o*sn;
        o = o*cs + e*sn;
        e = e2;
      }
      if (OUT_BF) {
        ushort2 uv; uv.x = f2bf(e); uv.y = f2bf(o);
        *(ushort2*)((unsigned short*)out_ + (size_t)(n0+t)*D_MODEL + ch0) = uv;
      } else {
        float2 fv; fv.x = e; fv.y = o;
        *(float2*)((float*)out_ + (size_t)(n0+t)*D_MODEL + ch0) = fv;
      }
    }
  }
}

__global__ __launch_bounds__(256) void proj_qkv_kernel(
    const void* x, const int* rules, const void* si, const void* so,
    const void* ri, const void* ro, const float* sel, float* out, int do_rope,
    const int* __restrict__ flag)
{
  if (*flag) proj_body<true, true, false>(x, rules, si, so, ri, ro, sel, (void*)out, do_rope);
  else       proj_body<false,false,false>(x, rules, si, so, ri, ro, sel, (void*)out, do_rope);
}

__global__ __launch_bounds__(256) void proj_o_kernel(
    const float* ain, const int* rules, const void* si, const void* so,
    const void* ri, const void* ro, const float* sel, void* out,
    const int* __restrict__ flag)
{
  if (*flag) proj_body<false,true, true >((const void*)ain, rules, si, so, ri, ro, sel, out, 0);
  else       proj_body<false,false,false>((const void*)ain, rules, si, so, ri, ro, sel, out, 0);
}

// ---------------------------------------------------------------------------
// Router mask -> per-(b,q) allowed-key list. One 64-thread wave per (b,q).
// rule r allowed <=> #causal keys with strictly greater M value < 32.
// ---------------------------------------------------------------------------
__global__ __launch_bounds__(64) void mask_kernel(
    const int* __restrict__ rules, const float* __restrict__ M,
    unsigned short* __restrict__ list, int* __restrict__ cntout)
{
  const int bid = blockIdx.x;              // b*1024 + qi
  const int b = bid >> 10, qi = bid & 1023;
  const int lane = threadIdx.x;
  __shared__ int rrow[SS];
  __shared__ float val[64];
  for (int i = lane; i < SS/4; i += 64)
    ((int4*)rrow)[i] = ((const int4*)(rules + b*SS))[i];
  __syncthreads();
  const int qrule = rrow[qi];
  const float myv = M[qrule*64 + lane];
  val[lane] = myv;
  int c = 0;
  for (int k = 0; k <= qi; k++) c += (rrow[k] == lane) ? 1 : 0;
  __syncthreads();
  int A = 0;
  for (int r = 0; r < 64; r++) {
    int cr = __shfl(c, r);
    A += (val[r] > myv) ? cr : 0;
  }
  unsigned long long allowed = __ballot(A < 32);
  unsigned short* lp = list + (size_t)bid*SS;
  int pos = 0;
  const unsigned long long lmask = (1ULL << lane) - 1ULL;
  for (int k0 = 0; k0 <= qi; k0 += 64) {
    int k = k0 + lane;
    int kc = (k <= qi) ? k : qi;
    bool ok = (k <= qi) && (((allowed >> rrow[kc]) & 1ULL) != 0ULL);
    unsigned long long bal = __ballot(ok);
    if (ok) lp[pos + __popcll(bal & lmask)] = (unsigned short)k;
    pos += __popcll(bal);
  }
  if (lane == 0) cntout[bid] = pos;
}

// ---------------------------------------------------------------------------
// Sparse attention, one wave per (b,q,h). Online softmax.
// QK: lane = key. PV: lane = (key-group g, dim-quad d4) with float4 loads.
// ---------------------------------------------------------------------------
__global__ __launch_bounds__(64) void attn_kernel(
    const float* __restrict__ qb, const float* __restrict__ kb, const float* __restrict__ vb,
    const unsigned short* __restrict__ list, const int* __restrict__ cnt,
    float* __restrict__ outb)
{
  const int qi = blockIdx.x, b = blockIdx.y, h = blockIdx.z;
  const int lane = threadIdx.x;
  const int nq = b*SS + qi;
  __shared__ float qs[64];
  __shared__ float wsh[64];
  __shared__ unsigned short keysh[64];
  qs[lane] = qb[(size_t)nq*D_MODEL + h*HEAD_DIM + lane] * 0.125f;  // fold 1/sqrt(64)
  const int total = cnt[nq];
  const unsigned short* lp = list + (size_t)nq*SS;
  const float* kbase = kb + (size_t)b*SS*D_MODEL + h*HEAD_DIM;
  const float* vbase = vb + (size_t)b*SS*D_MODEL + h*HEAD_DIM;
  const int g = lane >> 4, d4 = lane & 15;
  float4 acc = {0.f,0.f,0.f,0.f};
  float m = -1e30f, l = 0.f;
  __syncthreads();
  for (int c0 = 0; c0 < total; c0 += 64) {
    int nc = total - c0; if (nc > 64) nc = 64;
    float s = -1e30f;
    if (lane < nc) {
      int key = lp[c0 + lane];
      keysh[lane] = (unsigned short)key;
      const float4* kr = (const float4*)(kbase + (size_t)key*D_MODEL);
      const float4* q4 = (const float4*)qs;
      float sum = 0.f;
      #pragma unroll
      for (int t = 0; t < 16; t++) {
        float4 kv = kr[t];
        float4 qv = q4[t];
        sum += qv.x*kv.x + qv.y*kv.y + qv.z*kv.z + qv.w*kv.w;
      }
      s = sum;
    }
    float cm = s;
    #pragma unroll
    for (int off = 32; off; off >>= 1) cm = fmaxf(cm, __shfl_xor(cm, off));
    float newm = fmaxf(m, cm);
    float alpha = expf(m - newm);
    float w = (lane < nc) ? expf(s - newm) : 0.f;
    wsh[lane] = w;
    float lsum = w;
    #pragma unroll
    for (int off = 32; off; off >>= 1) lsum += __shfl_xor(lsum, off);
    l = l*alpha + lsum;
    m = newm;
    __syncthreads();
    acc.x *= alpha; acc.y *= alpha; acc.z *= alpha; acc.w *= alpha;
    for (int i = g; i < nc; i += 4) {
      float wi = wsh[i];
      int key = keysh[i];
      float4 v = *(const float4*)(vbase + (size_t)key*D_MODEL + d4*4);
      acc.x += wi*v.x; acc.y += wi*v.y; acc.z += wi*v.z; acc.w += wi*v.w;
    }
    __syncthreads();
  }
  acc.x += __shfl_xor(acc.x, 16); acc.y += __shfl_xor(acc.y, 16);
  acc.z += __shfl_xor(acc.z, 16); acc.w += __shfl_xor(acc.w, 16);
  acc.x += __shfl_xor(acc.x, 32); acc.y += __shfl_xor(acc.y, 32);
  acc.z += __shfl_xor(acc.z, 32); acc.w += __shfl_xor(acc.w, 32);
  if (lane < 16) {
    float invl = 1.0f / l;
    float4 o;
    o.x = acc.x*invl; o.y = acc.y*invl; o.z = acc.z*invl; o.w = acc.w*invl;
    *(float4*)(outb + (size_t)nq*D_MODEL + h*HEAD_DIM + d4*4) = o;
  }
}

// ---------------------------------------------------------------------------
extern "C" void kernel_launch(void* const* d_in, const int* in_sizes, int n_in,
                              void* d_out, int out_size, void* d_ws, size_t ws_size,
                              hipStream_t stream) {
  (void)in_sizes; (void)n_in; (void)out_size; (void)ws_size;
  const void* x    = d_in[0];
  const int* rules = (const int*)d_in[1];
  const void* q_si = d_in[2];  const void* q_so = d_in[3];
  const void* q_ri = d_in[4];  const void* q_ro = d_in[5];  const void* q_lg = d_in[6];
  const void* k_si = d_in[7];  const void* k_so = d_in[8];
  const void* k_ri = d_in[9];  const void* k_ro = d_in[10]; const void* k_lg = d_in[11];
  const void* v_si = d_in[12]; const void* v_so = d_in[13];
  const void* v_ri = d_in[14]; const void* v_ro = d_in[15]; const void* v_lg = d_in[16];
  const void* o_si = d_in[17]; const void* o_so = d_in[18];
  const void* o_ri = d_in[19]; const void* o_ro = d_in[20]; const void* o_lg = d_in[21];
  const void* rq   = d_in[22]; const void* rk   = d_in[23];

  char* ws = (char*)d_ws;
  float* qb   = (float*)(ws);                               // 16 MB (also attn out, in-place)
  float* kb   = (float*)(ws + (size_t)16*1024*1024);        // 16 MB
  float* vb   = (float*)(ws + (size_t)32*1024*1024);        // 16 MB
  unsigned short* listb = (unsigned short*)(ws + (size_t)48*1024*1024); // 8 MB
  int*   cntb = (int*)  (ws + (size_t)56*1024*1024);             // 16 KB
  float* Mt   = (float*)(ws + (size_t)56*1024*1024 + 16*1024);   // 16 KB
  float* selt = (float*)(ws + (size_t)56*1024*1024 + 32*1024);   // 16 KB
  int*   flag = (int*)  (ws + (size_t)56*1024*1024 + 48*1024);

  detect_kernel<<<1, 64, 0, stream>>>((const unsigned short*)x, flag);
  precompute_kernel<<<1, 256, 0, stream>>>(rq, rk, q_lg, k_lg, v_lg, o_lg, Mt, selt, flag);
  proj_qkv_kernel<<<NTOK/8, 256, 0, stream>>>(x, rules, q_si, q_so, q_ri, q_ro, selt,          qb, 1, flag);
  proj_qkv_kernel<<<NTOK/8, 256, 0, stream>>>(x, rules, k_si, k_so, k_ri, k_ro, selt + 1024,   kb, 1, flag);
  proj_qkv_kernel<<<NTOK/8, 256, 0, stream>>>(x, rules, v_si, v_so, v_ri, v_ro, selt + 2*1024, vb, 0, flag);
  mask_kernel<<<NTOK, 64, 0, stream>>>(rules, Mt, listb, cntb);
  attn_kernel<<<dim3(SS, BB, N_HEADS), 64, 0, stream>>>(qb, kb, vb, listb, cntb, qb);
  proj_o_kernel<<<NTOK/8, 256, 0, stream>>>(qb, rules, o_si, o_so, o_ri, o_ro, selt + 3*1024, d_out, flag);
}

// Round 4
// 445.919 us; speedup vs baseline: 1.9646x; 1.9646x over previous
//
#include <hip/hip_runtime.h>
#include <hip/hip_bf16.h>

#define D_MODEL 1024
#define N_HEADS 16
#define HEAD_DIM 64
#define NUM_RULES 64
#define RANK 8
#define SHARED_RANK 32
#define NUM_BLOCKS_ 16
#define BB 4
#define SS 1024
#define NTOK (BB*SS)

__device__ __forceinline__ float bf2f(unsigned short u) {
  unsigned int i = ((unsigned int)u) << 16;
  float f;
  __builtin_memcpy(&f, &i, 4);
  return f;
}
__device__ __forceinline__ unsigned short f2bf(float f) {
  __hip_bfloat16 h = __float2bfloat16(f);
  unsigned short u;
  __builtin_memcpy(&u, &h, 2);
  return u;
}
template<bool BF>
__device__ __forceinline__ float ldw(const void* p, size_t i) {
  if (BF) return bf2f(((const unsigned short*)p)[i]);
  else    return ((const float*)p)[i];
}

// ---------------------------------------------------------------------------
// Dtype detection
// ---------------------------------------------------------------------------
__global__ void detect_kernel(const unsigned short* __restrict__ x, int* __restrict__ flag) {
  const int lane = threadIdx.x;  // 64
  int good = 0;
  for (int i = 0; i < 4; i++) {
    unsigned short u = x[lane*4 + i];
    int e = (u >> 7) & 0xFF;
    good += (e == 0 || (e >= 100 && e <= 145)) ? 1 : 0;
  }
  for (int off = 32; off; off >>= 1) good += __shfl_xor(good, off);
  if (lane == 0) flag[0] = (good >= 224) ? 1 : 0;
}

// ---------------------------------------------------------------------------
// Precompute: M[64][64] and sel[4][64][16]
// ---------------------------------------------------------------------------
template<bool BF>
__device__ __forceinline__ void precompute_body(
    const void* rq, const void* rk,
    const void* qlg, const void* klg, const void* vlg, const void* olg,
    float* __restrict__ M, float* __restrict__ sel)
{
  __shared__ float rqn[64][8], rkn[64][8];
  const int tid = threadIdx.x;  // 256
  if (tid < 64) {
    float v[8]; float s = 0.f;
    for (int i = 0; i < 8; i++) { v[i] = ldw<BF>(rq, tid*8+i); s += v[i]*v[i]; }
    float inv = 1.0f / fmaxf(sqrtf(s), 1e-12f);
    for (int i = 0; i < 8; i++) rqn[tid][i] = v[i]*inv;
  } else if (tid < 128) {
    int r = tid - 64;
    float v[8]; float s = 0.f;
    for (int i = 0; i < 8; i++) { v[i] = ldw<BF>(rk, r*8+i); s += v[i]*v[i]; }
    float inv = 1.0f / fmaxf(sqrtf(s), 1e-12f);
    for (int i = 0; i < 8; i++) rkn[r][i] = v[i]*inv;
  }
  __syncthreads();
  const float LN8 = 2.0794415416798357f;  // 1/tau = ln(8)
  for (int idx = tid; idx < 64*64; idx += 256) {
    int i = idx >> 6, j = idx & 63;
    float d = 0.f;
    for (int t = 0; t < 8; t++) d += rqn[i][t]*rkn[j][t];
    M[idx] = d * LN8;
  }
  const void* lgs[4] = {qlg, klg, vlg, olg};
  {
    int r = tid & 63;
    const void* lg = lgs[tid >> 6];
    float e[NUM_BLOCKS_]; float mx = -1e30f;
    for (int b = 0; b < NUM_BLOCKS_; b++) {
      e[b] = ldw<BF>(lg, r*NUM_BLOCKS_ + b) * 4.0f;
      mx = fmaxf(mx, e[b]);
    }
    float s = 0.f;
    for (int b = 0; b < NUM_BLOCKS_; b++) { e[b] = expf(e[b]-mx); s += e[b]; }
    float inv = 1.0f/s;
    for (int b = 0; b < NUM_BLOCKS_; b++) sel[tid*NUM_BLOCKS_+b] = e[b]*inv;
  }
}

__global__ void precompute_kernel(
    const void* rq, const void* rk,
    const void* qlg, const void* klg, const void* vlg, const void* olg,
    float* M, float* sel, const int* __restrict__ flag)
{
  if (*flag) precompute_body<true >(rq, rk, qlg, klg, vlg, olg, M, sel);
  else       precompute_body<false>(rq, rk, qlg, klg, vlg, olg, M, sel);
}

// ---------------------------------------------------------------------------
// Rule-aware projection, 4 tokens per block (256 threads).
// NOTE: exactly ONE instantiation per __global__ kernel (LDS/VGPR discipline —
// R3 regression was dual-instantiation doubling LDS to 91.5KB + spill at 256 VGPR).
// ---------------------------------------------------------------------------
template<bool IN_BF, bool W_BF, bool OUT_BF>
__device__ __forceinline__ void proj_body(
    const void* __restrict__ xin_, const int* __restrict__ rules,
    const void* __restrict__ si, const void* __restrict__ so,
    const void* __restrict__ ri, const void* __restrict__ ro,
    const float* __restrict__ sel, void* __restrict__ out_, int do_rope)
{
  const int n0 = blockIdx.x * 4;
  const int tid = threadIdx.x;
  __shared__ float xs[4][D_MODEL + 4];   // 16.4 KB
  __shared__ float tpart[8][32][5];      // pad 5 (coprime 32): conflict-free reduce
  __shared__ float tt[32][5];
  __shared__ float hh[4][16][8];
  __shared__ float selb[4][16];
  __shared__ int rl[4];

  // ---- load x rows (4 x 1024) ----
  #pragma unroll
  for (int t = 0; t < 4; t++) {
    float4 f;
    if (IN_BF) {
      ushort4 u = ((const ushort4*)((const unsigned short*)xin_ + (size_t)(n0 + t)*D_MODEL))[tid];
      f.x = bf2f(u.x); f.y = bf2f(u.y); f.z = bf2f(u.z); f.w = bf2f(u.w);
    } else {
      f = ((const float4*)xin_)[(size_t)(n0 + t)*(D_MODEL/4) + tid];
    }
    *(float4*)&xs[t][tid*4] = f;
  }
  if (tid < 4) rl[tid] = rules[n0 + tid];
  __syncthreads();
  if (tid < 64) { int t = tid >> 4, blk = tid & 15; selb[t][blk] = sel[rl[t]*NUM_BLOCKS_ + blk]; }

  // ---- stage 1: tpart[c][j][t] = partial of t[tok][j] over d-chunk c ----
  {
    const int c = tid >> 5, j = tid & 31;
    float p[4] = {0.f,0.f,0.f,0.f};
    for (int d4 = 0; d4 < 32; d4++) {
      const int d = c*128 + d4*4;
      float w0 = ldw<W_BF>(si, (size_t)(d + 0)*SHARED_RANK + j);
      float w1 = ldw<W_BF>(si, (size_t)(d + 1)*SHARED_RANK + j);
      float w2 = ldw<W_BF>(si, (size_t)(d + 2)*SHARED_RANK + j);
      float w3 = ldw<W_BF>(si, (size_t)(d + 3)*SHARED_RANK + j);
      #pragma unroll
      for (int t = 0; t < 4; t++) {
        float4 xv = *(const float4*)&xs[t][d];
        p[t] += xv.x*w0 + xv.y*w1 + xv.z*w2 + xv.w*w3;
      }
    }
    #pragma unroll
    for (int t = 0; t < 4; t++) tpart[c][j][t] = p[t];
  }
  __syncthreads();

  // ---- stage 2: waves 0-1 reduce tt; waves 2-3 compute hh ----
  if (tid < 128) {
    const int j = tid & 31, t = tid >> 5;
    float s = 0.f;
    #pragma unroll
    for (int c = 0; c < 8; c++) s += tpart[c][j][t];
    tt[j][t] = s;
  } else {
    const int idx = tid - 128;
    const int t = idx >> 5, blk = (idx >> 1) & 15, r0 = (idx & 1)*4;
    const int rule = rl[t];
    float a0=0.f, a1=0.f, a2=0.f, a3=0.f;
    for (int k4 = 0; k4 < 16; k4++) {
      const int kk = ((k4 + blk) & 15) * 4;   // rotate to spread LDS banks
      float4 xv = *(const float4*)&xs[t][blk*64 + kk];
      #pragma unroll
      for (int q = 0; q < 4; q++) {
        const int k = kk + q;
        float w0,w1,w2,w3;
        if (W_BF) {
          ushort4 u = *(const ushort4*)((const unsigned short*)ri + (size_t)rule*512 + (size_t)k*8 + r0);
          w0=bf2f(u.x); w1=bf2f(u.y); w2=bf2f(u.z); w3=bf2f(u.w);
        } else {
          float4 u = *(const float4*)((const float*)ri + (size_t)rule*512 + (size_t)k*8 + r0);
          w0=u.x; w1=u.y; w2=u.z; w3=u.w;
        }
        float xq = (q==0)?xv.x:((q==1)?xv.y:((q==2)?xv.z:xv.w));
        a0 += xq*w0; a1 += xq*w1; a2 += xq*w2; a3 += xq*w3;
      }
    }
    hh[t][blk][r0+0]=a0; hh[t][blk][r0+1]=a1; hh[t][blk][r0+2]=a2; hh[t][blk][r0+3]=a3;
  }
  __syncthreads();

  // ---- epilogue: pair p -> channels (2p, 2p+1); base + lowrank + RoPE + store ----
  for (int u = 0; u < 2; u++) {
    const int p = tid + u*256;
    const int ch0 = 2*p;
    const int blk = p >> 5;
    const int ii = p & 31;
    float s0[4], s1[4];
    #pragma unroll
    for (int t = 0; t < 4; t++) { s0[t]=0.f; s1[t]=0.f; }
    for (int j = 0; j < 32; j++) {
      float w0, w1;
      if (W_BF) {
        ushort2 w = *(const ushort2*)((const unsigned short*)so + (size_t)j*D_MODEL + ch0);
        w0 = bf2f(w.x); w1 = bf2f(w.y);
      } else {
        float2 w = *(const float2*)((const float*)so + (size_t)j*D_MODEL + ch0);
        w0 = w.x; w1 = w.y;
      }
      #pragma unroll
      for (int t = 0; t < 4; t++) { float tv = tt[j][t]; s0[t] += tv*w0; s1[t] += tv*w1; }
    }
    float invf = 0.f;
    if (do_rope) invf = expf(-(float)(2*ii) * (9.210340371976184f/64.0f));
    const int tc = ch0 & 63;
    #pragma unroll
    for (int t = 0; t < 4; t++) {
      const int rule = rl[t];
      float a0=0.f, a1=0.f;
      #pragma unroll
      for (int r = 0; r < 8; r++) {
        float w0,w1;
        if (W_BF) {
          ushort2 w = *(const ushort2*)((const unsigned short*)ro + (size_t)rule*512 + (size_t)r*64 + tc);
          w0=bf2f(w.x); w1=bf2f(w.y);
        } else {
          float2 w = *(const float2*)((const float*)ro + (size_t)rule*512 + (size_t)r*64 + tc);
          w0=w.x; w1=w.y;
        }
        float hv = hh[t][blk][r];
        a0 += hv*w0; a1 += hv*w1;
      }
      float sb = selb[t][blk];
      float e = s0[t] + a0*sb;
      float o = s1[t] + a1*sb;
      if (do_rope) {
        float f = (float)((n0 + t) & (SS-1)) * invf;
        float sn, cs;
        sincosf(f, &sn, &cs);
        float e2 = e*cs - o*sn;
        o = o*cs + e*sn;
        e = e2;
      }
      if (OUT_BF) {
        ushort2 uv; uv.x = f2bf(e); uv.y = f2bf(o);
        *(ushort2*)((unsigned short*)out_ + (size_t)(n0+t)*D_MODEL + ch0) = uv;
      } else {
        float2 fv; fv.x = e; fv.y = o;
        *(float2*)((float*)out_ + (size_t)(n0+t)*D_MODEL + ch0) = fv;
      }
    }
  }
}

// Fused q/k/v projection: blockIdx.y selects weight set. One dtype per kernel.
__global__ __launch_bounds__(256) void proj_qkv_bf16(
    const void* x, const int* rules,
    const void* qsi, const void* qso, const void* qri, const void* qro,
    const void* ksi, const void* kso, const void* kri, const void* kro,
    const void* vsi, const void* vso, const void* vri, const void* vro,
    const float* sel, float* qb, float* kb, float* vb,
    const int* __restrict__ flag)
{
  if (!*flag) return;
  const int y = blockIdx.y;
  const void* si = (y==0)?qsi:((y==1)?ksi:vsi);
  const void* so = (y==0)?qso:((y==1)?kso:vso);
  const void* ri = (y==0)?qri:((y==1)?kri:vri);
  const void* ro = (y==0)?qro:((y==1)?kro:vro);
  float* out = (y==0)?qb:((y==1)?kb:vb);
  proj_body<true,true,false>(x, rules, si, so, ri, ro, sel + y*1024, (void*)out, (y<2)?1:0);
}

__global__ __launch_bounds__(256) void proj_qkv_f32(
    const void* x, const int* rules,
    const void* qsi, const void* qso, const void* qri, const void* qro,
    const void* ksi, const void* kso, const void* kri, const void* kro,
    const void* vsi, const void* vso, const void* vri, const void* vro,
    const float* sel, float* qb, float* kb, float* vb,
    const int* __restrict__ flag)
{
  if (*flag) return;
  const int y = blockIdx.y;
  const void* si = (y==0)?qsi:((y==1)?ksi:vsi);
  const void* so = (y==0)?qso:((y==1)?kso:vso);
  const void* ri = (y==0)?qri:((y==1)?kri:vri);
  const void* ro = (y==0)?qro:((y==1)?kro:vro);
  float* out = (y==0)?qb:((y==1)?kb:vb);
  proj_body<false,false,false>(x, rules, si, so, ri, ro, sel + y*1024, (void*)out, (y<2)?1:0);
}

__global__ __launch_bounds__(256) void proj_o_bf16(
    const float* ain, const int* rules, const void* si, const void* so,
    const void* ri, const void* ro, const float* sel, void* out,
    const int* __restrict__ flag)
{
  if (!*flag) return;
  proj_body<false,true,true>((const void*)ain, rules, si, so, ri, ro, sel, out, 0);
}

__global__ __launch_bounds__(256) void proj_o_f32(
    const float* ain, const int* rules, const void* si, const void* so,
    const void* ri, const void* ro, const float* sel, void* out,
    const int* __restrict__ flag)
{
  if (*flag) return;
  proj_body<false,false,false>((const void*)ain, rules, si, so, ri, ro, sel, out, 0);
}

// ---------------------------------------------------------------------------
// Router mask -> per-(b,q) allowed-key list. One 64-thread wave per (b,q).
// ---------------------------------------------------------------------------
__global__ __launch_bounds__(64) void mask_kernel(
    const int* __restrict__ rules, const float* __restrict__ M,
    unsigned short* __restrict__ list, int* __restrict__ cntout)
{
  const int bid = blockIdx.x;              // b*1024 + qi
  const int b = bid >> 10, qi = bid & 1023;
  const int lane = threadIdx.x;
  __shared__ int rrow[SS];
  __shared__ float val[64];
  for (int i = lane; i < SS/4; i += 64)
    ((int4*)rrow)[i] = ((const int4*)(rules + b*SS))[i];
  __syncthreads();
  const int qrule = rrow[qi];
  const float myv = M[qrule*64 + lane];
  val[lane] = myv;
  int c = 0;
  for (int k = 0; k <= qi; k++) c += (rrow[k] == lane) ? 1 : 0;
  __syncthreads();
  int A = 0;
  for (int r = 0; r < 64; r++) {
    int cr = __shfl(c, r);
    A += (val[r] > myv) ? cr : 0;
  }
  unsigned long long allowed = __ballot(A < 32);
  unsigned short* lp = list + (size_t)bid*SS;
  int pos = 0;
  const unsigned long long lmask = (1ULL << lane) - 1ULL;
  for (int k0 = 0; k0 <= qi; k0 += 64) {
    int k = k0 + lane;
    int kc = (k <= qi) ? k : qi;
    bool ok = (k <= qi) && (((allowed >> rrow[kc]) & 1ULL) != 0ULL);
    unsigned long long bal = __ballot(ok);
    if (ok) lp[pos + __popcll(bal & lmask)] = (unsigned short)k;
    pos += __popcll(bal);
  }
  if (lane == 0) cntout[bid] = pos;
}

// ---------------------------------------------------------------------------
// Sparse attention, one wave per (b,q,h). Online softmax.
// ---------------------------------------------------------------------------
__global__ __launch_bounds__(64) void attn_kernel(
    const float* __restrict__ qb, const float* __restrict__ kb, const float* __restrict__ vb,
    const unsigned short* __restrict__ list, const int* __restrict__ cnt,
    float* __restrict__ outb)
{
  const int qi = blockIdx.x, b = blockIdx.y, h = blockIdx.z;
  const int lane = threadIdx.x;
  const int nq = b*SS + qi;
  __shared__ float qs[64];
  __shared__ float wsh[64];
  __shared__ unsigned short keysh[64];
  qs[lane] = qb[(size_t)nq*D_MODEL + h*HEAD_DIM + lane] * 0.125f;
  const int total = cnt[nq];
  const unsigned short* lp = list + (size_t)nq*SS;
  const float* kbase = kb + (size_t)b*SS*D_MODEL + h*HEAD_DIM;
  const float* vbase = vb + (size_t)b*SS*D_MODEL + h*HEAD_DIM;
  const int g = lane >> 4, d4 = lane & 15;
  float4 acc = {0.f,0.f,0.f,0.f};
  float m = -1e30f, l = 0.f;
  __syncthreads();
  for (int c0 = 0; c0 < total; c0 += 64) {
    int nc = total - c0; if (nc > 64) nc = 64;
    float s = -1e30f;
    if (lane < nc) {
      int key = lp[c0 + lane];
      keysh[lane] = (unsigned short)key;
      const float4* kr = (const float4*)(kbase + (size_t)key*D_MODEL);
      const float4* q4 = (const float4*)qs;
      float sum = 0.f;
      #pragma unroll
      for (int t = 0; t < 16; t++) {
        float4 kv = kr[t];
        float4 qv = q4[t];
        sum += qv.x*kv.x + qv.y*kv.y + qv.z*kv.z + qv.w*kv.w;
      }
      s = sum;
    }
    float cm = s;
    #pragma unroll
    for (int off = 32; off; off >>= 1) cm = fmaxf(cm, __shfl_xor(cm, off));
    float newm = fmaxf(m, cm);
    float alpha = expf(m - newm);
    float w = (lane < nc) ? expf(s - newm) : 0.f;
    wsh[lane] = w;
    float lsum = w;
    #pragma unroll
    for (int off = 32; off; off >>= 1) lsum += __shfl_xor(lsum, off);
    l = l*alpha + lsum;
    m = newm;
    __syncthreads();
    acc.x *= alpha; acc.y *= alpha; acc.z *= alpha; acc.w *= alpha;
    for (int i = g; i < nc; i += 4) {
      float wi = wsh[i];
      int key = keysh[i];
      float4 v = *(const float4*)(vbase + (size_t)key*D_MODEL + d4*4);
      acc.x += wi*v.x; acc.y += wi*v.y; acc.z += wi*v.z; acc.w += wi*v.w;
    }
    __syncthreads();
  }
  acc.x += __shfl_xor(acc.x, 16); acc.y += __shfl_xor(acc.y, 16);
  acc.z += __shfl_xor(acc.z, 16); acc.w += __shfl_xor(acc.w, 16);
  acc.x += __shfl_xor(acc.x, 32); acc.y += __shfl_xor(acc.y, 32);
  acc.z += __shfl_xor(acc.z, 32); acc.w += __shfl_xor(acc.w, 32);
  if (lane < 16) {
    float invl = 1.0f / l;
    float4 o;
    o.x = acc.x*invl; o.y = acc.y*invl; o.z = acc.z*invl; o.w = acc.w*invl;
    *(float4*)(outb + (size_t)nq*D_MODEL + h*HEAD_DIM + d4*4) = o;
  }
}

// ---------------------------------------------------------------------------
extern "C" void kernel_launch(void* const* d_in, const int* in_sizes, int n_in,
                              void* d_out, int out_size, void* d_ws, size_t ws_size,
                              hipStream_t stream) {
  (void)in_sizes; (void)n_in; (void)out_size; (void)ws_size;
  const void* x    = d_in[0];
  const int* rules = (const int*)d_in[1];
  const void* q_si = d_in[2];  const void* q_so = d_in[3];
  const void* q_ri = d_in[4];  const void* q_ro = d_in[5];  const void* q_lg = d_in[6];
  const void* k_si = d_in[7];  const void* k_so = d_in[8];
  const void* k_ri = d_in[9];  const void* k_ro = d_in[10]; const void* k_lg = d_in[11];
  const void* v_si = d_in[12]; const void* v_so = d_in[13];
  const void* v_ri = d_in[14]; const void* v_ro = d_in[15]; const void* v_lg = d_in[16];
  const void* o_si = d_in[17]; const void* o_so = d_in[18];
  const void* o_ri = d_in[19]; const void* o_ro = d_in[20]; const void* o_lg = d_in[21];
  const void* rq   = d_in[22]; const void* rk   = d_in[23];

  char* ws = (char*)d_ws;
  float* qb   = (float*)(ws);                               // 16 MB (also attn out, in-place)
  float* kb   = (float*)(ws + (size_t)16*1024*1024);        // 16 MB
  float* vb   = (float*)(ws + (size_t)32*1024*1024);        // 16 MB
  unsigned short* listb = (unsigned short*)(ws + (size_t)48*1024*1024); // 8 MB
  int*   cntb = (int*)  (ws + (size_t)56*1024*1024);             // 16 KB
  float* Mt   = (float*)(ws + (size_t)56*1024*1024 + 16*1024);   // 16 KB
  float* selt = (float*)(ws + (size_t)56*1024*1024 + 32*1024);   // 16 KB
  int*   flag = (int*)  (ws + (size_t)56*1024*1024 + 48*1024);

  detect_kernel<<<1, 64, 0, stream>>>((const unsigned short*)x, flag);
  precompute_kernel<<<1, 256, 0, stream>>>(rq, rk, q_lg, k_lg, v_lg, o_lg, Mt, selt, flag);
  proj_qkv_bf16<<<dim3(NTOK/4, 3), 256, 0, stream>>>(x, rules,
      q_si, q_so, q_ri, q_ro, k_si, k_so, k_ri, k_ro, v_si, v_so, v_ri, v_ro,
      selt, qb, kb, vb, flag);
  proj_qkv_f32<<<dim3(NTOK/4, 3), 256, 0, stream>>>(x, rules,
      q_si, q_so, q_ri, q_ro, k_si, k_so, k_ri, k_ro, v_si, v_so, v_ri, v_ro,
      selt, qb, kb, vb, flag);
  mask_kernel<<<NTOK, 64, 0, stream>>>(rules, Mt, listb, cntb);
  attn_kernel<<<dim3(SS, BB, N_HEADS), 64, 0, stream>>>(qb, kb, vb, listb, cntb, qb);
  proj_o_bf16<<<NTOK/4, 256, 0, stream>>>(qb, rules, o_si, o_so, o_ri, o_ro, selt + 3*1024, d_out, flag);
  proj_o_f32 <<<NTOK/4, 256, 0, stream>>>(qb, rules, o_si, o_so, o_ri, o_ro, selt + 3*1024, d_out, flag);
}